// Round 9
// baseline (568.771 us; speedup 1.0000x reference)
//
#include <hip/hip_runtime.h>
#include <float.h>

// Problem constants
#define S_LEN 2048
#define BATCH 32
#define HCH   256
#define DCH   128
#define KCODES 512

typedef float  f32x4  __attribute__((ext_vector_type(4)));
typedef short  bf16x8 __attribute__((ext_vector_type(8)));
typedef short  short8 __attribute__((ext_vector_type(8)));

__device__ __forceinline__ float lrelu_f(float v) { return v >= 0.f ? v : 0.2f * v; }

// fp32 -> bf16 bits, round-to-nearest-even (finite values)
__device__ __forceinline__ short f2bf(float f) {
    unsigned u = __float_as_uint(f);
    u = u + 0x7fffu + ((u >> 16) & 1u);
    return (short)(u >> 16);
}
__device__ __forceinline__ float bf2f(unsigned short u) {
    return __uint_as_float(((unsigned)u) << 16);
}

// Async global->LDS 16B copy. LDS dest is wave-uniform base (+ lane*16 in HW),
// global src is per-lane.
__device__ __forceinline__ void async_copy16(short* lds, const short* g) {
    __builtin_amdgcn_global_load_lds(
        (const __attribute__((address_space(1))) unsigned int*)g,
        (__attribute__((address_space(3))) unsigned int*)lds,
        16, 0, 0);
}

// ---------------------------------------------------------------------------
// ALL prep work in ONE launch. Jobs selected by blockIdx.y.
// ---------------------------------------------------------------------------
__global__ void prep_all_kernel(
        const float* __restrict__ cb, short* __restrict__ cb_hi,
        short* __restrict__ cb_lo, float* __restrict__ cnorm,
        const float* __restrict__ ew2, short* __restrict__ w2_hi, short* __restrict__ w2_lo,
        const float* __restrict__ ew3, short* __restrict__ w3_hi, short* __restrict__ w3_lo,
        const float* __restrict__ dw1, short* __restrict__ wbf_d1,
        const float* __restrict__ dw2, short* __restrict__ wbf_d2,
        const float* __restrict__ dw3, float* __restrict__ w3t) {
    const int job = blockIdx.y;
    const int i = blockIdx.x * 256 + threadIdx.x;
    if (job == 0) {
        if (i < KCODES) {
            float s = 0.f;
            for (int d = 0; d < DCH; ++d) {
                float v = cb[i * DCH + d];
                s += v * v;
                short hi = f2bf(v);
                cb_hi[i * DCH + d] = hi;
                cb_lo[i * DCH + d] = f2bf(v - bf2f((unsigned short)hi));
            }
            cnorm[i] = s;
        }
    } else if (job == 1 || job == 2) {
        const int Cout = (job == 1) ? 256 : 128;
        const int Cin = 256;
        const float* src = (job == 1) ? ew2 : ew3;
        short* Wh = (job == 1) ? w2_hi : w3_hi;
        short* Wl = (job == 1) ? w2_lo : w3_lo;
        int total = 3 * Cout * Cin;
        if (i < total) {
            int t = i / (Cout * Cin);
            int rem = i - t * Cout * Cin;
            int co = rem / Cin;
            int ci = rem - co * Cin;
            float v = src[(co * Cin + ci) * 3 + t];
            short hi = f2bf(v);
            Wh[i] = hi;
            Wl[i] = f2bf(v - bf2f((unsigned short)hi));
        }
    } else if (job == 3 || job == 4) {
        const int Cin = (job == 3) ? 128 : 256;
        const float* src = (job == 3) ? dw1 : dw2;
        short* Wd = (job == 3) ? wbf_d1 : wbf_d2;
        int total = 3 * 256 * Cin;
        if (i < total) {
            int t = i / (256 * Cin);
            int rem = i - t * 256 * Cin;
            int co = rem / Cin;
            int ci = rem - co * Cin;
            Wd[i] = f2bf(src[(co * Cin + ci) * 3 + t]);
        }
    } else {
        if (i < 768) {
            int t = i / 256, ci = i - t * 256;
            w3t[i] = dw3[ci * 3 + t];
        }
    }
}

// ---------------------------------------------------------------------------
// Encoder conv1 channels-last: x[B][S] -> h hi/lo bf16 [B][S][256], lrelu.
// ---------------------------------------------------------------------------
__global__ __launch_bounds__(256) void enc_conv1_cl_kernel(
        const float* __restrict__ x, short* __restrict__ h_hi, short* __restrict__ h_lo,
        const float* __restrict__ w, const float* __restrict__ bias) {
    __shared__ float ws[HCH * 3];
    __shared__ float bs[HCH];
    int tid = threadIdx.x;
    for (int i = tid; i < HCH * 3; i += 256) ws[i] = w[i];
    for (int i = tid; i < HCH; i += 256) bs[i] = bias[i];
    __syncthreads();
    int b = blockIdx.y;
    int s = blockIdx.x * 32 + (tid >> 3);
    int cch = tid & 7;
    const float* xb = x + (size_t)b * S_LEN;
    float xm = (s > 0) ? xb[s - 1] : 0.f;
    float x0 = xb[s];
    float xp = (s < S_LEN - 1) ? xb[s + 1] : 0.f;
    size_t base = ((size_t)(b * S_LEN + s)) * HCH + cch * 32;
#pragma unroll
    for (int cc = 0; cc < 4; ++cc) {
        short8 oh, ol;
#pragma unroll
        for (int e = 0; e < 8; ++e) {
            int co = cch * 32 + cc * 8 + e;
            float v = ws[co * 3 + 0] * xm + ws[co * 3 + 1] * x0 + ws[co * 3 + 2] * xp + bs[co];
            v = lrelu_f(v);
            short hi = f2bf(v);
            oh[e] = hi;
            ol[e] = f2bf(v - bf2f((unsigned short)hi));
        }
        *(short8*)(h_hi + base + cc * 8) = oh;
        *(short8*)(h_lo + base + cc * 8) = ol;
    }
}

// ---------------------------------------------------------------------------
// Encoder split-bf16 MFMA conv (channels-last), k=3 SAME.  v6 (proven).
// ---------------------------------------------------------------------------
__global__ __launch_bounds__(256, 3) void conv_mfma_split(
        const short* __restrict__ in_hi, const short* __restrict__ in_lo,
        short* __restrict__ out_hi, short* __restrict__ out_lo,
        const short* __restrict__ wt_hi, const short* __restrict__ wt_lo,
        const float* __restrict__ bias, int Cin, int Cout, int do_lrelu) {
    __shared__ short smem[16640];

    const int tid  = threadIdx.x;
    const int lane = tid & 63;
    const int w    = tid >> 6;
    const int m    = lane & 15;
    const int q    = lane >> 4;
    const int sOff = (w & 1) * 64;
    const int cOff = (w >> 1) * 64;
    const int b    = blockIdx.z;
    const int s0   = blockIdx.x * 128;
    const int co0  = blockIdx.y * 128;

    f32x4 acc[4][4];
    f32x4 zero4 = {0.f, 0.f, 0.f, 0.f};
#pragma unroll
    for (int i = 0; i < 4; ++i)
#pragma unroll
        for (int j = 0; j < 4; ++j) acc[i][j] = zero4;

    const short* inhb = in_hi + (size_t)b * S_LEN * Cin;
    const short* inlb = in_lo + (size_t)b * S_LEN * Cin;
    const char* XhB = (const char*)smem;
    const char* XlB = XhB + 1040 * 16;

    for (int ci0 = 0; ci0 < Cin; ci0 += 64) {
        __syncthreads();

        if (s0 == 0 && tid < 16) {
            short8 z = {0, 0, 0, 0, 0, 0, 0, 0};
            int buf = tid >> 3, slot = tid & 7;            // row 0
            *(short8*)(smem + (size_t)(buf * 1040 + slot) * 8) = z;
        }
        if (s0 == S_LEN - 128 && tid < 16) {
            short8 z = {0, 0, 0, 0, 0, 0, 0, 0};
            int buf = tid >> 3, slot = tid & 7;            // row 129
            *(short8*)(smem + (size_t)(buf * 1040 + 129 * 8 + slot) * 8) = z;
        }

        for (int c = tid; c < 2080; c += 256) {
            int base_c = c - lane;                 // wave-uniform
            int buf  = (c >= 1040) ? 1 : 0;
            int cc   = c - buf * 1040;
            int r    = cc >> 3;
            int slot = cc & 7;
            int gch  = slot ^ (r & 7);
            int s    = s0 - 1 + r;
            short* ldsb = smem + (size_t)base_c * 8;
            const short* gp = (buf ? inlb : inhb) + (size_t)s * Cin + ci0 + gch * 8;
            if (s >= 0 && s < S_LEN) async_copy16(ldsb, gp);
        }
        __syncthreads();

#pragma unroll 1
        for (int ks = 0; ks < 2; ++ks) {
#pragma unroll
            for (int t = 0; t < 3; ++t) {
                bf16x8 ah[4], al[4], bh[4], bl[4];
#pragma unroll
                for (int i = 0; i < 4; ++i) {
                    int row = sOff + i * 16 + m + t;
                    int off = row * 128 + (((ks * 4 + q) ^ (row & 7)) << 4);
                    ah[i] = *(const bf16x8*)(XhB + off);
                    al[i] = *(const bf16x8*)(XlB + off);
                }
#pragma unroll
                for (int j = 0; j < 4; ++j) {
                    size_t woff = ((size_t)(t * Cout + co0 + cOff + j * 16 + m)) * Cin
                                  + ci0 + ks * 32 + q * 8;
                    bh[j] = *(const bf16x8*)(wt_hi + woff);
                    bl[j] = *(const bf16x8*)(wt_lo + woff);
                }
#pragma unroll
                for (int i = 0; i < 4; ++i)
#pragma unroll
                    for (int j = 0; j < 4; ++j) {
                        acc[i][j] = __builtin_amdgcn_mfma_f32_16x16x32_bf16(ah[i], bh[j], acc[i][j], 0, 0, 0);
                        acc[i][j] = __builtin_amdgcn_mfma_f32_16x16x32_bf16(ah[i], bl[j], acc[i][j], 0, 0, 0);
                        acc[i][j] = __builtin_amdgcn_mfma_f32_16x16x32_bf16(al[i], bh[j], acc[i][j], 0, 0, 0);
                    }
            }
        }
    }

    __syncthreads();

    short* ob = smem + w * 4096;
#pragma unroll
    for (int pass = 0; pass < 2; ++pass) {
#pragma unroll
        for (int j = 0; j < 4; ++j) {
            float bv = bias[co0 + cOff + j * 16 + m];
#pragma unroll
            for (int i = 0; i < 4; ++i)
#pragma unroll
                for (int r = 0; r < 4; ++r) {
                    float val = acc[i][j][r] + bv;
                    if (do_lrelu) val = lrelu_f(val);
                    short hi = f2bf(val);
                    short v = pass ? f2bf(val - bf2f((unsigned short)hi)) : hi;
                    ob[(i * 16 + q * 4 + r) * 64 + j * 16 + m] = v;
                }
        }
        short* outp = pass ? out_lo : out_hi;
#pragma unroll
        for (int itr = 0; itr < 8; ++itr) {
            int row = itr * 8 + (lane >> 3);
            int ch  = lane & 7;
            short8 v = *(const short8*)(ob + row * 64 + ch * 8);
            size_t goff = ((size_t)(b * S_LEN + s0 + sOff + row)) * Cout
                          + co0 + cOff + ch * 8;
            *(short8*)(outp + goff) = v;
        }
    }
}

// ---------------------------------------------------------------------------
// v10 FUSED conv3-enc + VQ, BM=64 (fixes R8's spills: conv acc[2][4]=32
// AGPRs is dumped by ALL waves into the 64x136 Z-tile right after the conv
// -> acc dead before VQ; no acc/vacc liveness overlap). VQ = R5's proven
// one-pass 64-row body with K-chunk 128 (vacc[4][2], bh/bl[2]) -> VQ-phase
// peak ~132 regs; both phases fit (256,3)'s 170-reg cap spill-free.
// z never touches HBM. Numerics bit-identical (same f2bf points, same MFMA
// d0 order, per-lane candidates ascending-k -> same first-min tie-break).
// LDS: X 1056 chunks (16,896B) overlaid by Z 17,408 shorts (34,816B)
// + red arrays ~2.3KB => ~37.1KB.
// ---------------------------------------------------------------------------
__global__ __launch_bounds__(256, 3) void conv3_vq_kernel(
        const short* __restrict__ in_hi, const short* __restrict__ in_lo,
        const short* __restrict__ wt_hi, const short* __restrict__ wt_lo,
        const float* __restrict__ bias,
        const short* __restrict__ cb_hi, const short* __restrict__ cb_lo,
        const float* __restrict__ cnorm, const float* __restrict__ cb,
        float* __restrict__ idx_f_out, short* __restrict__ zq,
        float* __restrict__ acc_vq) {
    __shared__ short smem[17408];
    __shared__ float redv[64][4];
    __shared__ int   redi[64][4];
    __shared__ int   idxs[64];
    __shared__ float wsum2[4];

    const int tid  = threadIdx.x;
    const int lane = tid & 63;
    const int w    = tid >> 6;
    const int m    = lane & 15;
    const int q    = lane >> 4;
    const int sOff = (w & 1) * 32;
    const int cOff = (w >> 1) * 64;
    const int b    = blockIdx.y;
    const int s0   = blockIdx.x * 64;
    const int Cin  = HCH;   // 256

    f32x4 acc[2][4];
    f32x4 zero4 = {0.f, 0.f, 0.f, 0.f};
#pragma unroll
    for (int i = 0; i < 2; ++i)
#pragma unroll
        for (int j = 0; j < 4; ++j) acc[i][j] = zero4;

    const short* inhb = in_hi + (size_t)b * S_LEN * Cin;
    const short* inlb = in_lo + (size_t)b * S_LEN * Cin;
    const char* XhB = (const char*)smem;
    const char* XlB = XhB + 528 * 16;

    // ---------------- conv phase (BM=64, Cout=128) ----------------
    for (int ci0 = 0; ci0 < Cin; ci0 += 64) {
        __syncthreads();

        if (s0 == 0 && tid < 16) {
            short8 z = {0, 0, 0, 0, 0, 0, 0, 0};
            int buf = tid >> 3, slot = tid & 7;            // row 0
            *(short8*)(smem + (size_t)(buf * 528 + slot) * 8) = z;
        }
        if (s0 == S_LEN - 64 && tid < 16) {
            short8 z = {0, 0, 0, 0, 0, 0, 0, 0};
            int buf = tid >> 3, slot = tid & 7;            // row 65
            *(short8*)(smem + (size_t)(buf * 528 + 65 * 8 + slot) * 8) = z;
        }

        // 1056 chunks: hi [0,528), lo [528,1056). LDS linear; global source
        // pre-swizzled: LDS slot c of row r holds global chunk (c ^ (r&7)).
        for (int c = tid; c < 1056; c += 256) {
            int base_c = c - lane;                 // wave-uniform
            int buf  = (c >= 528) ? 1 : 0;
            int cc   = c - buf * 528;
            int r    = cc >> 3;
            int slot = cc & 7;
            int gch  = slot ^ (r & 7);
            int s    = s0 - 1 + r;
            short* ldsb = smem + (size_t)base_c * 8;
            const short* gp = (buf ? inlb : inhb) + (size_t)s * Cin + ci0 + gch * 8;
            if (s >= 0 && s < S_LEN) async_copy16(ldsb, gp);
        }
        __syncthreads();

#pragma unroll 1
        for (int ks = 0; ks < 2; ++ks) {
#pragma unroll
            for (int t = 0; t < 3; ++t) {
                bf16x8 ah[2], al[2], bh[4], bl[4];
#pragma unroll
                for (int i = 0; i < 2; ++i) {
                    int row = sOff + i * 16 + m + t;
                    int off = row * 128 + (((ks * 4 + q) ^ (row & 7)) << 4);
                    ah[i] = *(const bf16x8*)(XhB + off);
                    al[i] = *(const bf16x8*)(XlB + off);
                }
#pragma unroll
                for (int j = 0; j < 4; ++j) {
                    size_t woff = ((size_t)(t * DCH + cOff + j * 16 + m)) * Cin
                                  + ci0 + ks * 32 + q * 8;
                    bh[j] = *(const bf16x8*)(wt_hi + woff);
                    bl[j] = *(const bf16x8*)(wt_lo + woff);
                }
#pragma unroll
                for (int i = 0; i < 2; ++i)
#pragma unroll
                    for (int j = 0; j < 4; ++j) {
                        acc[i][j] = __builtin_amdgcn_mfma_f32_16x16x32_bf16(ah[i], bh[j], acc[i][j], 0, 0, 0);
                        acc[i][j] = __builtin_amdgcn_mfma_f32_16x16x32_bf16(ah[i], bl[j], acc[i][j], 0, 0, 0);
                        acc[i][j] = __builtin_amdgcn_mfma_f32_16x16x32_bf16(al[i], bh[j], acc[i][j], 0, 0, 0);
                    }
            }
        }
    }

    __syncthreads();   // X dead; Z tile overlays it

    short* Zh = smem;
    short* Zl = smem + 8704;   // 64*136

    // Dump ALL conv accumulators (bias + hi/lo split) into Z -> acc dead.
#pragma unroll
    for (int j = 0; j < 4; ++j) {
        float bv = bias[cOff + j * 16 + m];
#pragma unroll
        for (int i = 0; i < 2; ++i)
#pragma unroll
            for (int r = 0; r < 4; ++r) {
                float val = acc[i][j][r] + bv;
                short hi = f2bf(val);
                short lo = f2bf(val - bf2f((unsigned short)hi));
                int rc = (sOff + i * 16 + q * 4 + r) * 136 + cOff + j * 16 + m;
                Zh[rc] = hi;
                Zl[rc] = lo;
            }
    }
    __syncthreads();

    const int n0 = b * S_LEN + s0;

    // ---------------- VQ phase (R5 body, K-chunk 128) ----------------
    float best[4][4];
    int besti[4][4];
#pragma unroll
    for (int i = 0; i < 4; ++i)
#pragma unroll
        for (int r = 0; r < 4; ++r) { best[i][r] = FLT_MAX; besti[i][r] = 0; }

#pragma unroll 1
    for (int k0 = 0; k0 < KCODES; k0 += 128) {
        f32x4 vacc[4][2];
#pragma unroll
        for (int i = 0; i < 4; ++i)
#pragma unroll
            for (int j = 0; j < 2; ++j) vacc[i][j] = zero4;

#pragma unroll
        for (int d0 = 0; d0 < DCH; d0 += 32) {
            bf16x8 ah[4], al[4], bh[2], bl[2];
#pragma unroll
            for (int i = 0; i < 4; ++i) {
                int row = i * 16 + m;
                ah[i] = *(const bf16x8*)(Zh + row * 136 + d0 + q * 8);
                al[i] = *(const bf16x8*)(Zl + row * 136 + d0 + q * 8);
            }
#pragma unroll
            for (int j = 0; j < 2; ++j) {
                size_t coff = (size_t)(k0 + w * 32 + j * 16 + m) * DCH + d0 + q * 8;
                bh[j] = *(const bf16x8*)(cb_hi + coff);
                bl[j] = *(const bf16x8*)(cb_lo + coff);
            }
#pragma unroll
            for (int i = 0; i < 4; ++i)
#pragma unroll
                for (int j = 0; j < 2; ++j) {
                    vacc[i][j] = __builtin_amdgcn_mfma_f32_16x16x32_bf16(ah[i], bh[j], vacc[i][j], 0, 0, 0);
                    vacc[i][j] = __builtin_amdgcn_mfma_f32_16x16x32_bf16(ah[i], bl[j], vacc[i][j], 0, 0, 0);
                    vacc[i][j] = __builtin_amdgcn_mfma_f32_16x16x32_bf16(al[i], bh[j], vacc[i][j], 0, 0, 0);
                }
        }
#pragma unroll
        for (int j = 0; j < 2; ++j) {
            int k = k0 + w * 32 + j * 16 + m;
            float cn = cnorm[k];
#pragma unroll
            for (int i = 0; i < 4; ++i)
#pragma unroll
                for (int r = 0; r < 4; ++r) {
                    float dv = cn - 2.f * vacc[i][j][r];
                    if (dv < best[i][r]) { best[i][r] = dv; besti[i][r] = k; }
                }
        }
    }

#pragma unroll
    for (int mask = 1; mask < 16; mask <<= 1) {
#pragma unroll
        for (int i = 0; i < 4; ++i)
#pragma unroll
            for (int r = 0; r < 4; ++r) {
                float ov = __shfl_xor(best[i][r], mask);
                int oi = __shfl_xor(besti[i][r], mask);
                if (ov < best[i][r] || (ov == best[i][r] && oi < besti[i][r])) {
                    best[i][r] = ov; besti[i][r] = oi;
                }
            }
    }
    if (m == 0) {
#pragma unroll
        for (int i = 0; i < 4; ++i)
#pragma unroll
            for (int r = 0; r < 4; ++r) {
                int srow = i * 16 + q * 4 + r;
                redv[srow][w] = best[i][r];
                redi[srow][w] = besti[i][r];
            }
    }
    __syncthreads();
    if (tid < 64) {
        float bv = redv[tid][0];
        int bi = redi[tid][0];
#pragma unroll
        for (int w2 = 1; w2 < 4; ++w2) {
            float v = redv[tid][w2];
            int ii = redi[tid][w2];
            if (v < bv || (v == bv && ii < bi)) { bv = v; bi = ii; }
        }
        idx_f_out[n0 + tid] = (float)bi;
        idxs[tid] = bi;
    }
    __syncthreads();

    // gather + zq + vq-sum (4 threads/row, 32 d each); Z still live in LDS.
    {
        int r = tid >> 2;
        int dpart = tid & 3;
        int k = idxs[r];
        const float* src = cb + (size_t)k * DCH + dpart * 32;
        const short* zh = Zh + r * 136 + dpart * 32;
        const short* zl = Zl + r * 136 + dpart * 32;
        size_t zoff = (size_t)(n0 + r) * DCH + dpart * 32;
        float sum = 0.f;
#pragma unroll
        for (int h = 0; h < 4; ++h) {
            float4 f0 = *(const float4*)(src + h * 8);
            float4 f1 = *(const float4*)(src + h * 8 + 4);
            bf16x8 vh = *(const bf16x8*)(zh + h * 8);
            bf16x8 vl = *(const bf16x8*)(zl + h * 8);
            float qv[8] = {f0.x, f0.y, f0.z, f0.w, f1.x, f1.y, f1.z, f1.w};
            short8 o;
#pragma unroll
            for (int e = 0; e < 8; ++e) {
                o[e] = f2bf(qv[e]);
                float zv = bf2f((unsigned short)vh[e]) + bf2f((unsigned short)vl[e]);
                float df = zv - qv[e];
                sum += df * df;
            }
            *(short8*)(zq + zoff + h * 8) = o;
        }
        for (int off = 32; off > 0; off >>= 1) sum += __shfl_down(sum, off);
        if (lane == 0) wsum2[w] = sum;
    }
    __syncthreads();
    if (tid == 0) atomicAdd(acc_vq, wsum2[0] + wsum2[1] + wsum2[2] + wsum2[3]);
}

// ---------------------------------------------------------------------------
// Decoder bf16 MFMA conv (channels-last) -- R5 original (492us-best run).
// ---------------------------------------------------------------------------
__global__ __launch_bounds__(256) void conv_mfma_cl(
        const short* __restrict__ in, short* __restrict__ out,
        const short* __restrict__ wt, const float* __restrict__ bias,
        int Cin) {
    __shared__ short smem[24672];
    short* Xs = smem;
    short* Ws = smem + 130 * 48;

    const int tid = threadIdx.x;
    const int lane = tid & 63;
    const int w = tid >> 6;
    const int m = lane & 15;
    const int q = lane >> 4;
    const int sOff = (w & 1) * 64;
    const int cOff = (w >> 1) * 64;
    const int b = blockIdx.z;
    const int s0 = blockIdx.x * 128;
    const int co0 = blockIdx.y * 128;

    f32x4 acc[4][4];
    f32x4 zero4 = {0.f, 0.f, 0.f, 0.f};
#pragma unroll
    for (int i = 0; i < 4; ++i)
#pragma unroll
        for (int j = 0; j < 4; ++j) acc[i][j] = zero4;

    const short* inb = in + (size_t)b * S_LEN * Cin;

    for (int ci0 = 0; ci0 < Cin; ci0 += 32) {
        __syncthreads();
        for (int c = tid; c < 520; c += 256) {
            int r = c >> 2, part = c & 3;
            int s = s0 - 1 + r;
            float4 v = make_float4(0.f, 0.f, 0.f, 0.f);
            if (s >= 0 && s < S_LEN)
                v = *(const float4*)(inb + (size_t)s * Cin + ci0 + part * 8);
            *(float4*)(Xs + r * 48 + part * 8) = v;
        }
        for (int c = tid; c < 1536; c += 256) {
            int t = c >> 9;
            int rem = c & 511;
            int cr = rem >> 2, part = rem & 3;
            float4 v = *(const float4*)(wt + ((size_t)(t * 256 + co0 + cr)) * Cin + ci0 + part * 8);
            *(float4*)(Ws + (t * 128 + cr) * 48 + part * 8) = v;
        }
        __syncthreads();

#pragma unroll
        for (int t = 0; t < 3; ++t) {
            bf16x8 a[4], bb[4];
#pragma unroll
            for (int i = 0; i < 4; ++i)
                a[i] = *(const bf16x8*)(Xs + (sOff + i * 16 + m + t) * 48 + q * 8);
#pragma unroll
            for (int j = 0; j < 4; ++j)
                bb[j] = *(const bf16x8*)(Ws + (t * 128 + cOff + j * 16 + m) * 48 + q * 8);
#pragma unroll
            for (int i = 0; i < 4; ++i)
#pragma unroll
                for (int j = 0; j < 4; ++j)
                    acc[i][j] = __builtin_amdgcn_mfma_f32_16x16x32_bf16(
                        a[i], bb[j], acc[i][j], 0, 0, 0);
        }
    }

    __syncthreads();

    short* ob = smem + w * (64 * 80);
#pragma unroll
    for (int j = 0; j < 4; ++j) {
        float bv = bias[co0 + cOff + j * 16 + m];
#pragma unroll
        for (int i = 0; i < 4; ++i) {
#pragma unroll
            for (int r = 0; r < 4; ++r) {
                float val = acc[i][j][r] + bv;
                val = lrelu_f(val);
                ob[(i * 16 + q * 4 + r) * 80 + j * 16 + m] = f2bf(val);
            }
        }
    }
    const int rsel = lane >> 3;
    const int off8 = (lane & 7) * 8;
#pragma unroll
    for (int pass = 0; pass < 8; ++pass) {
        int rr = pass * 8 + rsel;
        short8 v = *(const short8*)(ob + rr * 80 + off8);
        *(short8*)(out + ((size_t)(b * S_LEN + s0 + sOff + rr)) * 256 + co0 + cOff + off8) = v;
    }
}

// ---------------------------------------------------------------------------
// Decoder conv3, LDS-tiled: h[B][S][256] bf16 -> xr[B][S] fp32, + recon sum.
// ---------------------------------------------------------------------------
__global__ __launch_bounds__(256) void dec_conv3_tiled_kernel(
        const short* __restrict__ h, const float* __restrict__ w3t,
        const float* __restrict__ b3, const float* __restrict__ x,
        float* __restrict__ xr, float* __restrict__ acc_recon) {
    __shared__ short Zs[66 * 264];     // 34,848 B
    __shared__ float ws[3 * 256];
    __shared__ float wsum[4];
    int tid = threadIdx.x;
    int b = blockIdx.y;
    int s0 = blockIdx.x * 64;
    const short* hb = h + (size_t)b * S_LEN * HCH;
    for (int i = tid; i < 768; i += 256) ws[i] = w3t[i];
    for (int c = tid; c < 2112; c += 256) {
        int r = c >> 5, part = c & 31;
        int g = s0 - 1 + r;
        short8 v = {0, 0, 0, 0, 0, 0, 0, 0};
        if (g >= 0 && g < S_LEN)
            v = *(const short8*)(hb + (size_t)g * HCH + part * 8);
        *(short8*)(Zs + r * 264 + part * 8) = v;
    }
    __syncthreads();

    int quarter = tid & 3;
    int sl = tid >> 2;   // 0..63
    float a0 = 0.f, a1 = 0.f, a2 = 0.f, a3 = 0.f;
#pragma unroll
    for (int t = 0; t < 3; ++t) {
        const short* zrow = Zs + (sl + t) * 264 + quarter * 64;
        const float* wrow = ws + t * 256 + quarter * 64;
#pragma unroll
        for (int c = 0; c < 8; ++c) {
            bf16x8 v = *(const bf16x8*)(zrow + c * 8);
            float4 w0 = *(const float4*)(wrow + c * 8);
            float4 w1 = *(const float4*)(wrow + c * 8 + 4);
            a0 = fmaf(w0.x, bf2f((unsigned short)v[0]), a0);
            a1 = fmaf(w0.y, bf2f((unsigned short)v[1]), a1);
            a2 = fmaf(w0.z, bf2f((unsigned short)v[2]), a2);
            a3 = fmaf(w0.w, bf2f((unsigned short)v[3]), a3);
            a0 = fmaf(w1.x, bf2f((unsigned short)v[4]), a0);
            a1 = fmaf(w1.y, bf2f((unsigned short)v[5]), a1);
            a2 = fmaf(w1.z, bf2f((unsigned short)v[6]), a2);
            a3 = fmaf(w1.w, bf2f((unsigned short)v[7]), a3);
        }
    }
    float acc = (a0 + a1) + (a2 + a3);
    acc += __shfl_xor(acc, 1);
    acc += __shfl_xor(acc, 2);
    float df2 = 0.f;
    if (quarter == 0) {
        int s = s0 + sl;
        float tot = acc + b3[0];
        xr[b * S_LEN + s] = tot;
        float df = x[b * S_LEN + s] - tot;
        df2 = df * df;
    }
    for (int off = 32; off > 0; off >>= 1) df2 += __shfl_down(df2, off);
    int lane = tid & 63, wv = tid >> 6;
    if (lane == 0) wsum[wv] = df2;
    __syncthreads();
    if (tid == 0) atomicAdd(acc_recon, wsum[0] + wsum[1] + wsum[2] + wsum[3]);
}

// ---------------------------------------------------------------------------
__global__ void finalize_kernel(const float* __restrict__ accs, float* __restrict__ out) {
    if (threadIdx.x == 0) {
        float vqm = accs[0] / ((float)BATCH * S_LEN * DCH);
        float rm  = accs[1] / ((float)BATCH * S_LEN);
        float vq_loss = vqm * 0.05f;
        float commit  = vqm * 0.15f;
        float recon   = rm * 1.0f;
        out[0] = recon + vq_loss + commit;
        out[1] = recon;
        out[2] = vq_loss;
        out[3] = commit;
    }
}

// ---------------------------------------------------------------------------
extern "C" void kernel_launch(void* const* d_in, const int* in_sizes, int n_in,
                              void* d_out, int out_size, void* d_ws, size_t ws_size,
                              hipStream_t stream) {
    const float* x    = (const float*)d_in[0];
    const float* cb   = (const float*)d_in[1];
    const float* ew1  = (const float*)d_in[2];
    const float* eb1  = (const float*)d_in[3];
    const float* ew2  = (const float*)d_in[4];
    const float* eb2  = (const float*)d_in[5];
    const float* ew3  = (const float*)d_in[6];
    const float* eb3  = (const float*)d_in[7];
    const float* dw1  = (const float*)d_in[8];
    const float* db1  = (const float*)d_in[9];
    const float* dw2  = (const float*)d_in[10];
    const float* db2  = (const float*)d_in[11];
    const float* dw3  = (const float*)d_in[12];
    const float* db3  = (const float*)d_in[13];

    float* out = (float*)d_out;
    float* xr    = out;
    float* idx_f = out + BATCH * S_LEN;
    float* loss_out = out + 2 * BATCH * S_LEN;

    const size_t NH = (size_t)BATCH * S_LEN * HCH;   // 16,777,216
    const size_t ND = (size_t)BATCH * S_LEN * DCH;   // 8,388,608

    short* sp = (short*)d_ws;
    // arena A [0, 2*NH): h1 hi/lo -> after conv2: zq [0,ND) + h1d [NH,2NH)
    short* h1_hi = sp;
    short* h1_lo = sp + NH;
    short* zq_bf = sp;            // written by conv3_vq (h1 dead), read by cl#1
    short* h1d_bf = sp + NH;      // written by cl#1 (disjoint from zq: ND<NH)
    // arena B [2*NH, 4*NH): h2 hi/lo; h2d overlays h2_lo after conv3_vq
    short* h2_hi = sp + 2 * NH;
    short* h2_lo = sp + 3 * NH;
    short* h2d_bf = sp + 3 * NH;  // h2_lo dead after conv3_vq
    // small buffers
    short* sm = sp + 4 * NH;
    short* cb_hi = sm; sm += KCODES * DCH;
    short* cb_lo = sm; sm += KCODES * DCH;
    short* w2_hi = sm; sm += 3 * HCH * HCH;
    short* w2_lo = sm; sm += 3 * HCH * HCH;
    short* w3_hi = sm; sm += 3 * DCH * HCH;
    short* w3_lo = sm; sm += 3 * DCH * HCH;
    short* wbf_d1 = sm; sm += 3 * 256 * DCH;
    short* wbf_d2 = sm; sm += 3 * 256 * HCH;
    float* cnorm = (float*)sm;
    float* w3t = cnorm + KCODES;
    float* accs = w3t + 768;

    hipMemsetAsync(accs, 0, 2 * sizeof(float), stream);

    // single fused prep launch
    prep_all_kernel<<<dim3(768, 6), 256, 0, stream>>>(
        cb, cb_hi, cb_lo, cnorm, ew2, w2_hi, w2_lo, ew3, w3_hi, w3_lo,
        dw1, wbf_d1, dw2, wbf_d2, dw3, w3t);

    // encoder
    enc_conv1_cl_kernel<<<dim3(S_LEN / 32, BATCH), 256, 0, stream>>>(x, h1_hi, h1_lo, ew1, eb1);
    conv_mfma_split<<<dim3(S_LEN / 128, HCH / 128, BATCH), 256, 0, stream>>>(
        h1_hi, h1_lo, h2_hi, h2_lo, w2_hi, w2_lo, eb2, HCH, HCH, 1);

    // fused conv3-enc + VQ (BM=64; z never touches HBM)
    conv3_vq_kernel<<<dim3(S_LEN / 64, BATCH), 256, 0, stream>>>(
        h2_hi, h2_lo, w3_hi, w3_lo, eb3, cb_hi, cb_lo, cnorm, cb,
        idx_f, zq_bf, accs);

    // decoder (R5-original cl kernels)
    conv_mfma_cl<<<dim3(S_LEN / 128, 2, BATCH), 256, 0, stream>>>(
        zq_bf, h1d_bf, wbf_d1, db1, DCH);
    conv_mfma_cl<<<dim3(S_LEN / 128, 2, BATCH), 256, 0, stream>>>(
        h1d_bf, h2d_bf, wbf_d2, db2, HCH);
    dec_conv3_tiled_kernel<<<dim3(S_LEN / 64, BATCH), 256, 0, stream>>>(
        h2d_bf, w3t, db3, x, xr, accs + 1);

    finalize_kernel<<<1, 64, 0, stream>>>(accs, loss_out);
}

// Round 11
// 499.043 us; speedup vs baseline: 1.1397x; 1.1397x over previous
//
#include <hip/hip_runtime.h>
#include <float.h>

// Problem constants
#define S_LEN 2048
#define BATCH 32
#define HCH   256
#define DCH   128
#define KCODES 512

typedef float  f32x4  __attribute__((ext_vector_type(4)));
typedef short  bf16x8 __attribute__((ext_vector_type(8)));
typedef short  short8 __attribute__((ext_vector_type(8)));

__device__ __forceinline__ float lrelu_f(float v) { return v >= 0.f ? v : 0.2f * v; }

// fp32 -> bf16 bits, round-to-nearest-even (finite values)
__device__ __forceinline__ short f2bf(float f) {
    unsigned u = __float_as_uint(f);
    u = u + 0x7fffu + ((u >> 16) & 1u);
    return (short)(u >> 16);
}
__device__ __forceinline__ float bf2f(unsigned short u) {
    return __uint_as_float(((unsigned)u) << 16);
}

// Async global->LDS 16B copy. LDS dest is wave-uniform base (+ lane*16 in HW),
// global src is per-lane.
__device__ __forceinline__ void async_copy16(short* lds, const short* g) {
    __builtin_amdgcn_global_load_lds(
        (const __attribute__((address_space(1))) unsigned int*)g,
        (__attribute__((address_space(3))) unsigned int*)lds,
        16, 0, 0);
}

// ---------------------------------------------------------------------------
// ALL prep work in ONE launch. Jobs selected by blockIdx.y.
// ---------------------------------------------------------------------------
__global__ void prep_all_kernel(
        const float* __restrict__ cb, short* __restrict__ cb_hi,
        short* __restrict__ cb_lo, float* __restrict__ cnorm,
        const float* __restrict__ ew2, short* __restrict__ w2_hi, short* __restrict__ w2_lo,
        const float* __restrict__ ew3, short* __restrict__ w3_hi, short* __restrict__ w3_lo,
        const float* __restrict__ dw1, short* __restrict__ wbf_d1,
        const float* __restrict__ dw2, short* __restrict__ wbf_d2,
        const float* __restrict__ dw3, float* __restrict__ w3t) {
    const int job = blockIdx.y;
    const int i = blockIdx.x * 256 + threadIdx.x;
    if (job == 0) {
        if (i < KCODES) {
            float s = 0.f;
            for (int d = 0; d < DCH; ++d) {
                float v = cb[i * DCH + d];
                s += v * v;
                short hi = f2bf(v);
                cb_hi[i * DCH + d] = hi;
                cb_lo[i * DCH + d] = f2bf(v - bf2f((unsigned short)hi));
            }
            cnorm[i] = s;
        }
    } else if (job == 1 || job == 2) {
        const int Cout = (job == 1) ? 256 : 128;
        const int Cin = 256;
        const float* src = (job == 1) ? ew2 : ew3;
        short* Wh = (job == 1) ? w2_hi : w3_hi;
        short* Wl = (job == 1) ? w2_lo : w3_lo;
        int total = 3 * Cout * Cin;
        if (i < total) {
            int t = i / (Cout * Cin);
            int rem = i - t * Cout * Cin;
            int co = rem / Cin;
            int ci = rem - co * Cin;
            float v = src[(co * Cin + ci) * 3 + t];
            short hi = f2bf(v);
            Wh[i] = hi;
            Wl[i] = f2bf(v - bf2f((unsigned short)hi));
        }
    } else if (job == 3 || job == 4) {
        const int Cin = (job == 3) ? 128 : 256;
        const float* src = (job == 3) ? dw1 : dw2;
        short* Wd = (job == 3) ? wbf_d1 : wbf_d2;
        int total = 3 * 256 * Cin;
        if (i < total) {
            int t = i / (256 * Cin);
            int rem = i - t * 256 * Cin;
            int co = rem / Cin;
            int ci = rem - co * Cin;
            Wd[i] = f2bf(src[(co * Cin + ci) * 3 + t]);
        }
    } else {
        if (i < 768) {
            int t = i / 256, ci = i - t * 256;
            w3t[i] = dw3[ci * 3 + t];
        }
    }
}

// ---------------------------------------------------------------------------
// Encoder conv1 channels-last: x[B][S] -> h hi/lo bf16 [B][S][256], lrelu.
// ---------------------------------------------------------------------------
__global__ __launch_bounds__(256) void enc_conv1_cl_kernel(
        const float* __restrict__ x, short* __restrict__ h_hi, short* __restrict__ h_lo,
        const float* __restrict__ w, const float* __restrict__ bias) {
    __shared__ float ws[HCH * 3];
    __shared__ float bs[HCH];
    int tid = threadIdx.x;
    for (int i = tid; i < HCH * 3; i += 256) ws[i] = w[i];
    for (int i = tid; i < HCH; i += 256) bs[i] = bias[i];
    __syncthreads();
    int b = blockIdx.y;
    int s = blockIdx.x * 32 + (tid >> 3);
    int cch = tid & 7;
    const float* xb = x + (size_t)b * S_LEN;
    float xm = (s > 0) ? xb[s - 1] : 0.f;
    float x0 = xb[s];
    float xp = (s < S_LEN - 1) ? xb[s + 1] : 0.f;
    size_t base = ((size_t)(b * S_LEN + s)) * HCH + cch * 32;
#pragma unroll
    for (int cc = 0; cc < 4; ++cc) {
        short8 oh, ol;
#pragma unroll
        for (int e = 0; e < 8; ++e) {
            int co = cch * 32 + cc * 8 + e;
            float v = ws[co * 3 + 0] * xm + ws[co * 3 + 1] * x0 + ws[co * 3 + 2] * xp + bs[co];
            v = lrelu_f(v);
            short hi = f2bf(v);
            oh[e] = hi;
            ol[e] = f2bf(v - bf2f((unsigned short)hi));
        }
        *(short8*)(h_hi + base + cc * 8) = oh;
        *(short8*)(h_lo + base + cc * 8) = ol;
    }
}

// ---------------------------------------------------------------------------
// Encoder split-bf16 MFMA conv (channels-last), k=3 SAME.  v6 (proven).
// ---------------------------------------------------------------------------
__global__ __launch_bounds__(256, 3) void conv_mfma_split(
        const short* __restrict__ in_hi, const short* __restrict__ in_lo,
        short* __restrict__ out_hi, short* __restrict__ out_lo,
        const short* __restrict__ wt_hi, const short* __restrict__ wt_lo,
        const float* __restrict__ bias, int Cin, int Cout, int do_lrelu) {
    __shared__ short smem[16640];

    const int tid  = threadIdx.x;
    const int lane = tid & 63;
    const int w    = tid >> 6;
    const int m    = lane & 15;
    const int q    = lane >> 4;
    const int sOff = (w & 1) * 64;
    const int cOff = (w >> 1) * 64;
    const int b    = blockIdx.z;
    const int s0   = blockIdx.x * 128;
    const int co0  = blockIdx.y * 128;

    f32x4 acc[4][4];
    f32x4 zero4 = {0.f, 0.f, 0.f, 0.f};
#pragma unroll
    for (int i = 0; i < 4; ++i)
#pragma unroll
        for (int j = 0; j < 4; ++j) acc[i][j] = zero4;

    const short* inhb = in_hi + (size_t)b * S_LEN * Cin;
    const short* inlb = in_lo + (size_t)b * S_LEN * Cin;
    const char* XhB = (const char*)smem;
    const char* XlB = XhB + 1040 * 16;

    for (int ci0 = 0; ci0 < Cin; ci0 += 64) {
        __syncthreads();

        if (s0 == 0 && tid < 16) {
            short8 z = {0, 0, 0, 0, 0, 0, 0, 0};
            int buf = tid >> 3, slot = tid & 7;            // row 0
            *(short8*)(smem + (size_t)(buf * 1040 + slot) * 8) = z;
        }
        if (s0 == S_LEN - 128 && tid < 16) {
            short8 z = {0, 0, 0, 0, 0, 0, 0, 0};
            int buf = tid >> 3, slot = tid & 7;            // row 129
            *(short8*)(smem + (size_t)(buf * 1040 + 129 * 8 + slot) * 8) = z;
        }

        for (int c = tid; c < 2080; c += 256) {
            int base_c = c - lane;                 // wave-uniform
            int buf  = (c >= 1040) ? 1 : 0;
            int cc   = c - buf * 1040;
            int r    = cc >> 3;
            int slot = cc & 7;
            int gch  = slot ^ (r & 7);
            int s    = s0 - 1 + r;
            short* ldsb = smem + (size_t)base_c * 8;
            const short* gp = (buf ? inlb : inhb) + (size_t)s * Cin + ci0 + gch * 8;
            if (s >= 0 && s < S_LEN) async_copy16(ldsb, gp);
        }
        __syncthreads();

#pragma unroll 1
        for (int ks = 0; ks < 2; ++ks) {
#pragma unroll
            for (int t = 0; t < 3; ++t) {
                bf16x8 ah[4], al[4], bh[4], bl[4];
#pragma unroll
                for (int i = 0; i < 4; ++i) {
                    int row = sOff + i * 16 + m + t;
                    int off = row * 128 + (((ks * 4 + q) ^ (row & 7)) << 4);
                    ah[i] = *(const bf16x8*)(XhB + off);
                    al[i] = *(const bf16x8*)(XlB + off);
                }
#pragma unroll
                for (int j = 0; j < 4; ++j) {
                    size_t woff = ((size_t)(t * Cout + co0 + cOff + j * 16 + m)) * Cin
                                  + ci0 + ks * 32 + q * 8;
                    bh[j] = *(const bf16x8*)(wt_hi + woff);
                    bl[j] = *(const bf16x8*)(wt_lo + woff);
                }
#pragma unroll
                for (int i = 0; i < 4; ++i)
#pragma unroll
                    for (int j = 0; j < 4; ++j) {
                        acc[i][j] = __builtin_amdgcn_mfma_f32_16x16x32_bf16(ah[i], bh[j], acc[i][j], 0, 0, 0);
                        acc[i][j] = __builtin_amdgcn_mfma_f32_16x16x32_bf16(ah[i], bl[j], acc[i][j], 0, 0, 0);
                        acc[i][j] = __builtin_amdgcn_mfma_f32_16x16x32_bf16(al[i], bh[j], acc[i][j], 0, 0, 0);
                    }
            }
        }
    }

    __syncthreads();

    short* ob = smem + w * 4096;
#pragma unroll
    for (int pass = 0; pass < 2; ++pass) {
#pragma unroll
        for (int j = 0; j < 4; ++j) {
            float bv = bias[co0 + cOff + j * 16 + m];
#pragma unroll
            for (int i = 0; i < 4; ++i)
#pragma unroll
                for (int r = 0; r < 4; ++r) {
                    float val = acc[i][j][r] + bv;
                    if (do_lrelu) val = lrelu_f(val);
                    short hi = f2bf(val);
                    short v = pass ? f2bf(val - bf2f((unsigned short)hi)) : hi;
                    ob[(i * 16 + q * 4 + r) * 64 + j * 16 + m] = v;
                }
        }
        short* outp = pass ? out_lo : out_hi;
#pragma unroll
        for (int itr = 0; itr < 8; ++itr) {
            int row = itr * 8 + (lane >> 3);
            int ch  = lane & 7;
            short8 v = *(const short8*)(ob + row * 64 + ch * 8);
            size_t goff = ((size_t)(b * S_LEN + s0 + sOff + row)) * Cout
                          + co0 + cOff + ch * 8;
            *(short8*)(outp + goff) = v;
        }
    }
}

// ---------------------------------------------------------------------------
// v11 FUSED conv3-enc + VQ, BM=64, __launch_bounds__(256,2).
// R8 spilled: acc/vacc liveness OVERLAP under a 256-reg cap.
// R9 spilled: no overlap but a 170-reg cap ((256,3)) < VQ-phase's ~190.
// v11 = no overlap (BM=64 acc[2][4] dumped to LDS Z before VQ) AND the
// 256-reg cap: conv phase ~110 regs, VQ phase ~180 regs -- both fit.
// VQ body restored to R5's exact proven form (K-chunk 256, vacc[4][4]).
// Grid 1024 blocks @ 2 blocks/CU. z never touches HBM.
// ---------------------------------------------------------------------------
__global__ __launch_bounds__(256, 2) void conv3_vq_kernel(
        const short* __restrict__ in_hi, const short* __restrict__ in_lo,
        const short* __restrict__ wt_hi, const short* __restrict__ wt_lo,
        const float* __restrict__ bias,
        const short* __restrict__ cb_hi, const short* __restrict__ cb_lo,
        const float* __restrict__ cnorm, const float* __restrict__ cb,
        float* __restrict__ idx_f_out, short* __restrict__ zq,
        float* __restrict__ acc_vq) {
    __shared__ short smem[17408];
    __shared__ float redv[64][4];
    __shared__ int   redi[64][4];
    __shared__ int   idxs[64];
    __shared__ float wsum2[4];

    const int tid  = threadIdx.x;
    const int lane = tid & 63;
    const int w    = tid >> 6;
    const int m    = lane & 15;
    const int q    = lane >> 4;
    const int sOff = (w & 1) * 32;
    const int cOff = (w >> 1) * 64;
    const int b    = blockIdx.y;
    const int s0   = blockIdx.x * 64;
    const int Cin  = HCH;   // 256

    f32x4 acc[2][4];
    f32x4 zero4 = {0.f, 0.f, 0.f, 0.f};
#pragma unroll
    for (int i = 0; i < 2; ++i)
#pragma unroll
        for (int j = 0; j < 4; ++j) acc[i][j] = zero4;

    const short* inhb = in_hi + (size_t)b * S_LEN * Cin;
    const short* inlb = in_lo + (size_t)b * S_LEN * Cin;
    const char* XhB = (const char*)smem;
    const char* XlB = XhB + 528 * 16;

    // ---------------- conv phase (BM=64, Cout=128) ----------------
    for (int ci0 = 0; ci0 < Cin; ci0 += 64) {
        __syncthreads();

        if (s0 == 0 && tid < 16) {
            short8 z = {0, 0, 0, 0, 0, 0, 0, 0};
            int buf = tid >> 3, slot = tid & 7;            // row 0
            *(short8*)(smem + (size_t)(buf * 528 + slot) * 8) = z;
        }
        if (s0 == S_LEN - 64 && tid < 16) {
            short8 z = {0, 0, 0, 0, 0, 0, 0, 0};
            int buf = tid >> 3, slot = tid & 7;            // row 65
            *(short8*)(smem + (size_t)(buf * 528 + 65 * 8 + slot) * 8) = z;
        }

        // 1056 chunks: hi [0,528), lo [528,1056). LDS linear; global source
        // pre-swizzled: LDS slot c of row r holds global chunk (c ^ (r&7)).
        for (int c = tid; c < 1056; c += 256) {
            int base_c = c - lane;                 // wave-uniform
            int buf  = (c >= 528) ? 1 : 0;
            int cc   = c - buf * 528;
            int r    = cc >> 3;
            int slot = cc & 7;
            int gch  = slot ^ (r & 7);
            int s    = s0 - 1 + r;
            short* ldsb = smem + (size_t)base_c * 8;
            const short* gp = (buf ? inlb : inhb) + (size_t)s * Cin + ci0 + gch * 8;
            if (s >= 0 && s < S_LEN) async_copy16(ldsb, gp);
        }
        __syncthreads();

#pragma unroll 1
        for (int ks = 0; ks < 2; ++ks) {
#pragma unroll
            for (int t = 0; t < 3; ++t) {
                bf16x8 ah[2], al[2], bh[4], bl[4];
#pragma unroll
                for (int i = 0; i < 2; ++i) {
                    int row = sOff + i * 16 + m + t;
                    int off = row * 128 + (((ks * 4 + q) ^ (row & 7)) << 4);
                    ah[i] = *(const bf16x8*)(XhB + off);
                    al[i] = *(const bf16x8*)(XlB + off);
                }
#pragma unroll
                for (int j = 0; j < 4; ++j) {
                    size_t woff = ((size_t)(t * DCH + cOff + j * 16 + m)) * Cin
                                  + ci0 + ks * 32 + q * 8;
                    bh[j] = *(const bf16x8*)(wt_hi + woff);
                    bl[j] = *(const bf16x8*)(wt_lo + woff);
                }
#pragma unroll
                for (int i = 0; i < 2; ++i)
#pragma unroll
                    for (int j = 0; j < 4; ++j) {
                        acc[i][j] = __builtin_amdgcn_mfma_f32_16x16x32_bf16(ah[i], bh[j], acc[i][j], 0, 0, 0);
                        acc[i][j] = __builtin_amdgcn_mfma_f32_16x16x32_bf16(ah[i], bl[j], acc[i][j], 0, 0, 0);
                        acc[i][j] = __builtin_amdgcn_mfma_f32_16x16x32_bf16(al[i], bh[j], acc[i][j], 0, 0, 0);
                    }
            }
        }
    }

    __syncthreads();   // X dead; Z tile overlays it

    short* Zh = smem;
    short* Zl = smem + 8704;   // 64*136

    // Dump ALL conv accumulators (bias + hi/lo split) into Z -> acc dead
    // BEFORE the VQ phase begins (no liveness overlap).
#pragma unroll
    for (int j = 0; j < 4; ++j) {
        float bv = bias[cOff + j * 16 + m];
#pragma unroll
        for (int i = 0; i < 2; ++i)
#pragma unroll
            for (int r = 0; r < 4; ++r) {
                float val = acc[i][j][r] + bv;
                short hi = f2bf(val);
                short lo = f2bf(val - bf2f((unsigned short)hi));
                int rc = (sOff + i * 16 + q * 4 + r) * 136 + cOff + j * 16 + m;
                Zh[rc] = hi;
                Zl[rc] = lo;
            }
    }
    __syncthreads();

    const int n0 = b * S_LEN + s0;

    // ---------------- VQ phase (R5's exact body, K-chunk 256) ----------------
    float best[4][4];
    int besti[4][4];
#pragma unroll
    for (int i = 0; i < 4; ++i)
#pragma unroll
        for (int r = 0; r < 4; ++r) { best[i][r] = FLT_MAX; besti[i][r] = 0; }

#pragma unroll 1
    for (int k0 = 0; k0 < KCODES; k0 += 256) {
        f32x4 vacc[4][4];
#pragma unroll
        for (int i = 0; i < 4; ++i)
#pragma unroll
            for (int j = 0; j < 4; ++j) vacc[i][j] = zero4;

#pragma unroll
        for (int d0 = 0; d0 < DCH; d0 += 32) {
            bf16x8 ah[4], al[4], bh[4], bl[4];
#pragma unroll
            for (int i = 0; i < 4; ++i) {
                int row = i * 16 + m;
                ah[i] = *(const bf16x8*)(Zh + row * 136 + d0 + q * 8);
                al[i] = *(const bf16x8*)(Zl + row * 136 + d0 + q * 8);
            }
#pragma unroll
            for (int j = 0; j < 4; ++j) {
                size_t coff = (size_t)(k0 + w * 64 + j * 16 + m) * DCH + d0 + q * 8;
                bh[j] = *(const bf16x8*)(cb_hi + coff);
                bl[j] = *(const bf16x8*)(cb_lo + coff);
            }
#pragma unroll
            for (int i = 0; i < 4; ++i)
#pragma unroll
                for (int j = 0; j < 4; ++j) {
                    vacc[i][j] = __builtin_amdgcn_mfma_f32_16x16x32_bf16(ah[i], bh[j], vacc[i][j], 0, 0, 0);
                    vacc[i][j] = __builtin_amdgcn_mfma_f32_16x16x32_bf16(ah[i], bl[j], vacc[i][j], 0, 0, 0);
                    vacc[i][j] = __builtin_amdgcn_mfma_f32_16x16x32_bf16(al[i], bh[j], vacc[i][j], 0, 0, 0);
                }
        }
#pragma unroll
        for (int j = 0; j < 4; ++j) {
            int k = k0 + w * 64 + j * 16 + m;
            float cn = cnorm[k];
#pragma unroll
            for (int i = 0; i < 4; ++i)
#pragma unroll
                for (int r = 0; r < 4; ++r) {
                    float dv = cn - 2.f * vacc[i][j][r];
                    if (dv < best[i][r]) { best[i][r] = dv; besti[i][r] = k; }
                }
        }
    }

#pragma unroll
    for (int mask = 1; mask < 16; mask <<= 1) {
#pragma unroll
        for (int i = 0; i < 4; ++i)
#pragma unroll
            for (int r = 0; r < 4; ++r) {
                float ov = __shfl_xor(best[i][r], mask);
                int oi = __shfl_xor(besti[i][r], mask);
                if (ov < best[i][r] || (ov == best[i][r] && oi < besti[i][r])) {
                    best[i][r] = ov; besti[i][r] = oi;
                }
            }
    }
    if (m == 0) {
#pragma unroll
        for (int i = 0; i < 4; ++i)
#pragma unroll
            for (int r = 0; r < 4; ++r) {
                int srow = i * 16 + q * 4 + r;
                redv[srow][w] = best[i][r];
                redi[srow][w] = besti[i][r];
            }
    }
    __syncthreads();
    if (tid < 64) {
        float bv = redv[tid][0];
        int bi = redi[tid][0];
#pragma unroll
        for (int w2 = 1; w2 < 4; ++w2) {
            float v = redv[tid][w2];
            int ii = redi[tid][w2];
            if (v < bv || (v == bv && ii < bi)) { bv = v; bi = ii; }
        }
        idx_f_out[n0 + tid] = (float)bi;
        idxs[tid] = bi;
    }
    __syncthreads();

    // gather + zq + vq-sum (4 threads/row, 32 d each); Z still live in LDS.
    {
        int r = tid >> 2;
        int dpart = tid & 3;
        int k = idxs[r];
        const float* src = cb + (size_t)k * DCH + dpart * 32;
        const short* zh = Zh + r * 136 + dpart * 32;
        const short* zl = Zl + r * 136 + dpart * 32;
        size_t zoff = (size_t)(n0 + r) * DCH + dpart * 32;
        float sum = 0.f;
#pragma unroll
        for (int h = 0; h < 4; ++h) {
            float4 f0 = *(const float4*)(src + h * 8);
            float4 f1 = *(const float4*)(src + h * 8 + 4);
            bf16x8 vh = *(const bf16x8*)(zh + h * 8);
            bf16x8 vl = *(const bf16x8*)(zl + h * 8);
            float qv[8] = {f0.x, f0.y, f0.z, f0.w, f1.x, f1.y, f1.z, f1.w};
            short8 o;
#pragma unroll
            for (int e = 0; e < 8; ++e) {
                o[e] = f2bf(qv[e]);
                float zv = bf2f((unsigned short)vh[e]) + bf2f((unsigned short)vl[e]);
                float df = zv - qv[e];
                sum += df * df;
            }
            *(short8*)(zq + zoff + h * 8) = o;
        }
        for (int off = 32; off > 0; off >>= 1) sum += __shfl_down(sum, off);
        if (lane == 0) wsum2[w] = sum;
    }
    __syncthreads();
    if (tid == 0) atomicAdd(acc_vq, wsum2[0] + wsum2[1] + wsum2[2] + wsum2[3]);
}

// ---------------------------------------------------------------------------
// Decoder bf16 MFMA conv (channels-last) -- R5 original (492us-best run).
// ---------------------------------------------------------------------------
__global__ __launch_bounds__(256) void conv_mfma_cl(
        const short* __restrict__ in, short* __restrict__ out,
        const short* __restrict__ wt, const float* __restrict__ bias,
        int Cin) {
    __shared__ short smem[24672];
    short* Xs = smem;
    short* Ws = smem + 130 * 48;

    const int tid = threadIdx.x;
    const int lane = tid & 63;
    const int w = tid >> 6;
    const int m = lane & 15;
    const int q = lane >> 4;
    const int sOff = (w & 1) * 64;
    const int cOff = (w >> 1) * 64;
    const int b = blockIdx.z;
    const int s0 = blockIdx.x * 128;
    const int co0 = blockIdx.y * 128;

    f32x4 acc[4][4];
    f32x4 zero4 = {0.f, 0.f, 0.f, 0.f};
#pragma unroll
    for (int i = 0; i < 4; ++i)
#pragma unroll
        for (int j = 0; j < 4; ++j) acc[i][j] = zero4;

    const short* inb = in + (size_t)b * S_LEN * Cin;

    for (int ci0 = 0; ci0 < Cin; ci0 += 32) {
        __syncthreads();
        for (int c = tid; c < 520; c += 256) {
            int r = c >> 2, part = c & 3;
            int s = s0 - 1 + r;
            float4 v = make_float4(0.f, 0.f, 0.f, 0.f);
            if (s >= 0 && s < S_LEN)
                v = *(const float4*)(inb + (size_t)s * Cin + ci0 + part * 8);
            *(float4*)(Xs + r * 48 + part * 8) = v;
        }
        for (int c = tid; c < 1536; c += 256) {
            int t = c >> 9;
            int rem = c & 511;
            int cr = rem >> 2, part = rem & 3;
            float4 v = *(const float4*)(wt + ((size_t)(t * 256 + co0 + cr)) * Cin + ci0 + part * 8);
            *(float4*)(Ws + (t * 128 + cr) * 48 + part * 8) = v;
        }
        __syncthreads();

#pragma unroll
        for (int t = 0; t < 3; ++t) {
            bf16x8 a[4], bb[4];
#pragma unroll
            for (int i = 0; i < 4; ++i)
                a[i] = *(const bf16x8*)(Xs + (sOff + i * 16 + m + t) * 48 + q * 8);
#pragma unroll
            for (int j = 0; j < 4; ++j)
                bb[j] = *(const bf16x8*)(Ws + (t * 128 + cOff + j * 16 + m) * 48 + q * 8);
#pragma unroll
            for (int i = 0; i < 4; ++i)
#pragma unroll
                for (int j = 0; j < 4; ++j)
                    acc[i][j] = __builtin_amdgcn_mfma_f32_16x16x32_bf16(
                        a[i], bb[j], acc[i][j], 0, 0, 0);
        }
    }

    __syncthreads();

    short* ob = smem + w * (64 * 80);
#pragma unroll
    for (int j = 0; j < 4; ++j) {
        float bv = bias[co0 + cOff + j * 16 + m];
#pragma unroll
        for (int i = 0; i < 4; ++i) {
#pragma unroll
            for (int r = 0; r < 4; ++r) {
                float val = acc[i][j][r] + bv;
                val = lrelu_f(val);
                ob[(i * 16 + q * 4 + r) * 80 + j * 16 + m] = f2bf(val);
            }
        }
    }
    const int rsel = lane >> 3;
    const int off8 = (lane & 7) * 8;
#pragma unroll
    for (int pass = 0; pass < 8; ++pass) {
        int rr = pass * 8 + rsel;
        short8 v = *(const short8*)(ob + rr * 80 + off8);
        *(short8*)(out + ((size_t)(b * S_LEN + s0 + sOff + rr)) * 256 + co0 + cOff + off8) = v;
    }
}

// ---------------------------------------------------------------------------
// Decoder conv3, LDS-tiled: h[B][S][256] bf16 -> xr[B][S] fp32, + recon sum.
// ---------------------------------------------------------------------------
__global__ __launch_bounds__(256) void dec_conv3_tiled_kernel(
        const short* __restrict__ h, const float* __restrict__ w3t,
        const float* __restrict__ b3, const float* __restrict__ x,
        float* __restrict__ xr, float* __restrict__ acc_recon) {
    __shared__ short Zs[66 * 264];     // 34,848 B
    __shared__ float ws[3 * 256];
    __shared__ float wsum[4];
    int tid = threadIdx.x;
    int b = blockIdx.y;
    int s0 = blockIdx.x * 64;
    const short* hb = h + (size_t)b * S_LEN * HCH;
    for (int i = tid; i < 768; i += 256) ws[i] = w3t[i];
    for (int c = tid; c < 2112; c += 256) {
        int r = c >> 5, part = c & 31;
        int g = s0 - 1 + r;
        short8 v = {0, 0, 0, 0, 0, 0, 0, 0};
        if (g >= 0 && g < S_LEN)
            v = *(const short8*)(hb + (size_t)g * HCH + part * 8);
        *(short8*)(Zs + r * 264 + part * 8) = v;
    }
    __syncthreads();

    int quarter = tid & 3;
    int sl = tid >> 2;   // 0..63
    float a0 = 0.f, a1 = 0.f, a2 = 0.f, a3 = 0.f;
#pragma unroll
    for (int t = 0; t < 3; ++t) {
        const short* zrow = Zs + (sl + t) * 264 + quarter * 64;
        const float* wrow = ws + t * 256 + quarter * 64;
#pragma unroll
        for (int c = 0; c < 8; ++c) {
            bf16x8 v = *(const bf16x8*)(zrow + c * 8);
            float4 w0 = *(const float4*)(wrow + c * 8);
            float4 w1 = *(const float4*)(wrow + c * 8 + 4);
            a0 = fmaf(w0.x, bf2f((unsigned short)v[0]), a0);
            a1 = fmaf(w0.y, bf2f((unsigned short)v[1]), a1);
            a2 = fmaf(w0.z, bf2f((unsigned short)v[2]), a2);
            a3 = fmaf(w0.w, bf2f((unsigned short)v[3]), a3);
            a0 = fmaf(w1.x, bf2f((unsigned short)v[4]), a0);
            a1 = fmaf(w1.y, bf2f((unsigned short)v[5]), a1);
            a2 = fmaf(w1.z, bf2f((unsigned short)v[6]), a2);
            a3 = fmaf(w1.w, bf2f((unsigned short)v[7]), a3);
        }
    }
    float acc = (a0 + a1) + (a2 + a3);
    acc += __shfl_xor(acc, 1);
    acc += __shfl_xor(acc, 2);
    float df2 = 0.f;
    if (quarter == 0) {
        int s = s0 + sl;
        float tot = acc + b3[0];
        xr[b * S_LEN + s] = tot;
        float df = x[b * S_LEN + s] - tot;
        df2 = df * df;
    }
    for (int off = 32; off > 0; off >>= 1) df2 += __shfl_down(df2, off);
    int lane = tid & 63, wv = tid >> 6;
    if (lane == 0) wsum[wv] = df2;
    __syncthreads();
    if (tid == 0) atomicAdd(acc_recon, wsum[0] + wsum[1] + wsum[2] + wsum[3]);
}

// ---------------------------------------------------------------------------
__global__ void finalize_kernel(const float* __restrict__ accs, float* __restrict__ out) {
    if (threadIdx.x == 0) {
        float vqm = accs[0] / ((float)BATCH * S_LEN * DCH);
        float rm  = accs[1] / ((float)BATCH * S_LEN);
        float vq_loss = vqm * 0.05f;
        float commit  = vqm * 0.15f;
        float recon   = rm * 1.0f;
        out[0] = recon + vq_loss + commit;
        out[1] = recon;
        out[2] = vq_loss;
        out[3] = commit;
    }
}

// ---------------------------------------------------------------------------
extern "C" void kernel_launch(void* const* d_in, const int* in_sizes, int n_in,
                              void* d_out, int out_size, void* d_ws, size_t ws_size,
                              hipStream_t stream) {
    const float* x    = (const float*)d_in[0];
    const float* cb   = (const float*)d_in[1];
    const float* ew1  = (const float*)d_in[2];
    const float* eb1  = (const float*)d_in[3];
    const float* ew2  = (const float*)d_in[4];
    const float* eb2  = (const float*)d_in[5];
    const float* ew3  = (const float*)d_in[6];
    const float* eb3  = (const float*)d_in[7];
    const float* dw1  = (const float*)d_in[8];
    const float* db1  = (const float*)d_in[9];
    const float* dw2  = (const float*)d_in[10];
    const float* db2  = (const float*)d_in[11];
    const float* dw3  = (const float*)d_in[12];
    const float* db3  = (const float*)d_in[13];

    float* out = (float*)d_out;
    float* xr    = out;
    float* idx_f = out + BATCH * S_LEN;
    float* loss_out = out + 2 * BATCH * S_LEN;

    const size_t NH = (size_t)BATCH * S_LEN * HCH;   // 16,777,216
    const size_t ND = (size_t)BATCH * S_LEN * DCH;   // 8,388,608

    short* sp = (short*)d_ws;
    // arena A [0, 2*NH): h1 hi/lo -> after conv2: zq [0,ND) + h1d [NH,2NH)
    short* h1_hi = sp;
    short* h1_lo = sp + NH;
    short* zq_bf = sp;            // written by conv3_vq (h1 dead), read by cl#1
    short* h1d_bf = sp + NH;      // written by cl#1 (disjoint from zq: ND<NH)
    // arena B [2*NH, 4*NH): h2 hi/lo; h2d overlays h2_lo after conv3_vq
    short* h2_hi = sp + 2 * NH;
    short* h2_lo = sp + 3 * NH;
    short* h2d_bf = sp + 3 * NH;  // h2_lo dead after conv3_vq
    // small buffers
    short* sm = sp + 4 * NH;
    short* cb_hi = sm; sm += KCODES * DCH;
    short* cb_lo = sm; sm += KCODES * DCH;
    short* w2_hi = sm; sm += 3 * HCH * HCH;
    short* w2_lo = sm; sm += 3 * HCH * HCH;
    short* w3_hi = sm; sm += 3 * DCH * HCH;
    short* w3_lo = sm; sm += 3 * DCH * HCH;
    short* wbf_d1 = sm; sm += 3 * 256 * DCH;
    short* wbf_d2 = sm; sm += 3 * 256 * HCH;
    float* cnorm = (float*)sm;
    float* w3t = cnorm + KCODES;
    float* accs = w3t + 768;

    hipMemsetAsync(accs, 0, 2 * sizeof(float), stream);

    // single fused prep launch
    prep_all_kernel<<<dim3(768, 6), 256, 0, stream>>>(
        cb, cb_hi, cb_lo, cnorm, ew2, w2_hi, w2_lo, ew3, w3_hi, w3_lo,
        dw1, wbf_d1, dw2, wbf_d2, dw3, w3t);

    // encoder
    enc_conv1_cl_kernel<<<dim3(S_LEN / 32, BATCH), 256, 0, stream>>>(x, h1_hi, h1_lo, ew1, eb1);
    conv_mfma_split<<<dim3(S_LEN / 128, HCH / 128, BATCH), 256, 0, stream>>>(
        h1_hi, h1_lo, h2_hi, h2_lo, w2_hi, w2_lo, eb2, HCH, HCH, 1);

    // fused conv3-enc + VQ (BM=64, (256,2); z never touches HBM)
    conv3_vq_kernel<<<dim3(S_LEN / 64, BATCH), 256, 0, stream>>>(
        h2_hi, h2_lo, w3_hi, w3_lo, eb3, cb_hi, cb_lo, cnorm, cb,
        idx_f, zq_bf, accs);

    // decoder (R5-original cl kernels)
    conv_mfma_cl<<<dim3(S_LEN / 128, 2, BATCH), 256, 0, stream>>>(
        zq_bf, h1d_bf, wbf_d1, db1, DCH);
    conv_mfma_cl<<<dim3(S_LEN / 128, 2, BATCH), 256, 0, stream>>>(
        h1d_bf, h2d_bf, wbf_d2, db2, HCH);
    dec_conv3_tiled_kernel<<<dim3(S_LEN / 64, BATCH), 256, 0, stream>>>(
        h2d_bf, w3t, db3, x, xr, accs + 1);

    finalize_kernel<<<1, 64, 0, stream>>>(accs, loss_out);
}

// Round 12
// 482.950 us; speedup vs baseline: 1.1777x; 1.0333x over previous
//
#include <hip/hip_runtime.h>
#include <float.h>

// Problem constants
#define S_LEN 2048
#define BATCH 32
#define HCH   256
#define DCH   128
#define KCODES 512

typedef float  f32x4  __attribute__((ext_vector_type(4)));
typedef short  bf16x8 __attribute__((ext_vector_type(8)));
typedef short  short8 __attribute__((ext_vector_type(8)));

__device__ __forceinline__ float lrelu_f(float v) { return v >= 0.f ? v : 0.2f * v; }

// fp32 -> bf16 bits, round-to-nearest-even (finite values)
__device__ __forceinline__ short f2bf(float f) {
    unsigned u = __float_as_uint(f);
    u = u + 0x7fffu + ((u >> 16) & 1u);
    return (short)(u >> 16);
}
__device__ __forceinline__ float bf2f(unsigned short u) {
    return __uint_as_float(((unsigned)u) << 16);
}

// Async global->LDS 16B copy. LDS dest is wave-uniform base (+ lane*16 in HW),
// global src is per-lane.
__device__ __forceinline__ void async_copy16(short* lds, const short* g) {
    __builtin_amdgcn_global_load_lds(
        (const __attribute__((address_space(1))) unsigned int*)g,
        (__attribute__((address_space(3))) unsigned int*)lds,
        16, 0, 0);
}

// ---------------------------------------------------------------------------
// ALL prep work in ONE launch (proven R8/R11). Jobs selected by blockIdx.y.
// ---------------------------------------------------------------------------
__global__ void prep_all_kernel(
        const float* __restrict__ cb, short* __restrict__ cb_hi,
        short* __restrict__ cb_lo, float* __restrict__ cnorm,
        const float* __restrict__ ew2, short* __restrict__ w2_hi, short* __restrict__ w2_lo,
        const float* __restrict__ ew3, short* __restrict__ w3_hi, short* __restrict__ w3_lo,
        const float* __restrict__ dw1, short* __restrict__ wbf_d1,
        const float* __restrict__ dw2, short* __restrict__ wbf_d2,
        const float* __restrict__ dw3, float* __restrict__ w3t) {
    const int job = blockIdx.y;
    const int i = blockIdx.x * 256 + threadIdx.x;
    if (job == 0) {
        if (i < KCODES) {
            float s = 0.f;
            for (int d = 0; d < DCH; ++d) {
                float v = cb[i * DCH + d];
                s += v * v;
                short hi = f2bf(v);
                cb_hi[i * DCH + d] = hi;
                cb_lo[i * DCH + d] = f2bf(v - bf2f((unsigned short)hi));
            }
            cnorm[i] = s;
        }
    } else if (job == 1 || job == 2) {
        const int Cout = (job == 1) ? 256 : 128;
        const int Cin = 256;
        const float* src = (job == 1) ? ew2 : ew3;
        short* Wh = (job == 1) ? w2_hi : w3_hi;
        short* Wl = (job == 1) ? w2_lo : w3_lo;
        int total = 3 * Cout * Cin;
        if (i < total) {
            int t = i / (Cout * Cin);
            int rem = i - t * Cout * Cin;
            int co = rem / Cin;
            int ci = rem - co * Cin;
            float v = src[(co * Cin + ci) * 3 + t];
            short hi = f2bf(v);
            Wh[i] = hi;
            Wl[i] = f2bf(v - bf2f((unsigned short)hi));
        }
    } else if (job == 3 || job == 4) {
        const int Cin = (job == 3) ? 128 : 256;
        const float* src = (job == 3) ? dw1 : dw2;
        short* Wd = (job == 3) ? wbf_d1 : wbf_d2;
        int total = 3 * 256 * Cin;
        if (i < total) {
            int t = i / (256 * Cin);
            int rem = i - t * 256 * Cin;
            int co = rem / Cin;
            int ci = rem - co * Cin;
            Wd[i] = f2bf(src[(co * Cin + ci) * 3 + t]);
        }
    } else {
        if (i < 768) {
            int t = i / 256, ci = i - t * 256;
            w3t[i] = dw3[ci * 3 + t];
        }
    }
}

// ---------------------------------------------------------------------------
// Encoder conv1 channels-last: x[B][S] -> h hi/lo bf16 [B][S][256], lrelu.
// ---------------------------------------------------------------------------
__global__ __launch_bounds__(256) void enc_conv1_cl_kernel(
        const float* __restrict__ x, short* __restrict__ h_hi, short* __restrict__ h_lo,
        const float* __restrict__ w, const float* __restrict__ bias) {
    __shared__ float ws[HCH * 3];
    __shared__ float bs[HCH];
    int tid = threadIdx.x;
    for (int i = tid; i < HCH * 3; i += 256) ws[i] = w[i];
    for (int i = tid; i < HCH; i += 256) bs[i] = bias[i];
    __syncthreads();
    int b = blockIdx.y;
    int s = blockIdx.x * 32 + (tid >> 3);
    int cch = tid & 7;
    const float* xb = x + (size_t)b * S_LEN;
    float xm = (s > 0) ? xb[s - 1] : 0.f;
    float x0 = xb[s];
    float xp = (s < S_LEN - 1) ? xb[s + 1] : 0.f;
    size_t base = ((size_t)(b * S_LEN + s)) * HCH + cch * 32;
#pragma unroll
    for (int cc = 0; cc < 4; ++cc) {
        short8 oh, ol;
#pragma unroll
        for (int e = 0; e < 8; ++e) {
            int co = cch * 32 + cc * 8 + e;
            float v = ws[co * 3 + 0] * xm + ws[co * 3 + 1] * x0 + ws[co * 3 + 2] * xp + bs[co];
            v = lrelu_f(v);
            short hi = f2bf(v);
            oh[e] = hi;
            ol[e] = f2bf(v - bf2f((unsigned short)hi));
        }
        *(short8*)(h_hi + base + cc * 8) = oh;
        *(short8*)(h_lo + base + cc * 8) = ol;
    }
}

// ---------------------------------------------------------------------------
// Encoder split-bf16 MFMA conv (channels-last), k=3 SAME.  v6 (proven:
// 122us @ Cin=256, WRITE=logical min, spill-free, 0 K-loop bank conflicts).
// ---------------------------------------------------------------------------
__global__ __launch_bounds__(256, 3) void conv_mfma_split(
        const short* __restrict__ in_hi, const short* __restrict__ in_lo,
        short* __restrict__ out_hi, short* __restrict__ out_lo,
        const short* __restrict__ wt_hi, const short* __restrict__ wt_lo,
        const float* __restrict__ bias, int Cin, int Cout, int do_lrelu) {
    __shared__ short smem[16640];

    const int tid  = threadIdx.x;
    const int lane = tid & 63;
    const int w    = tid >> 6;
    const int m    = lane & 15;
    const int q    = lane >> 4;
    const int sOff = (w & 1) * 64;
    const int cOff = (w >> 1) * 64;
    const int b    = blockIdx.z;
    const int s0   = blockIdx.x * 128;
    const int co0  = blockIdx.y * 128;

    f32x4 acc[4][4];
    f32x4 zero4 = {0.f, 0.f, 0.f, 0.f};
#pragma unroll
    for (int i = 0; i < 4; ++i)
#pragma unroll
        for (int j = 0; j < 4; ++j) acc[i][j] = zero4;

    const short* inhb = in_hi + (size_t)b * S_LEN * Cin;
    const short* inlb = in_lo + (size_t)b * S_LEN * Cin;
    const char* XhB = (const char*)smem;
    const char* XlB = XhB + 1040 * 16;

    for (int ci0 = 0; ci0 < Cin; ci0 += 64) {
        __syncthreads();

        if (s0 == 0 && tid < 16) {
            short8 z = {0, 0, 0, 0, 0, 0, 0, 0};
            int buf = tid >> 3, slot = tid & 7;            // row 0
            *(short8*)(smem + (size_t)(buf * 1040 + slot) * 8) = z;
        }
        if (s0 == S_LEN - 128 && tid < 16) {
            short8 z = {0, 0, 0, 0, 0, 0, 0, 0};
            int buf = tid >> 3, slot = tid & 7;            // row 129
            *(short8*)(smem + (size_t)(buf * 1040 + 129 * 8 + slot) * 8) = z;
        }

        for (int c = tid; c < 2080; c += 256) {
            int base_c = c - lane;                 // wave-uniform
            int buf  = (c >= 1040) ? 1 : 0;
            int cc   = c - buf * 1040;
            int r    = cc >> 3;
            int slot = cc & 7;
            int gch  = slot ^ (r & 7);
            int s    = s0 - 1 + r;
            short* ldsb = smem + (size_t)base_c * 8;
            const short* gp = (buf ? inlb : inhb) + (size_t)s * Cin + ci0 + gch * 8;
            if (s >= 0 && s < S_LEN) async_copy16(ldsb, gp);
        }
        __syncthreads();

#pragma unroll 1
        for (int ks = 0; ks < 2; ++ks) {
#pragma unroll
            for (int t = 0; t < 3; ++t) {
                bf16x8 ah[4], al[4], bh[4], bl[4];
#pragma unroll
                for (int i = 0; i < 4; ++i) {
                    int row = sOff + i * 16 + m + t;
                    int off = row * 128 + (((ks * 4 + q) ^ (row & 7)) << 4);
                    ah[i] = *(const bf16x8*)(XhB + off);
                    al[i] = *(const bf16x8*)(XlB + off);
                }
#pragma unroll
                for (int j = 0; j < 4; ++j) {
                    size_t woff = ((size_t)(t * Cout + co0 + cOff + j * 16 + m)) * Cin
                                  + ci0 + ks * 32 + q * 8;
                    bh[j] = *(const bf16x8*)(wt_hi + woff);
                    bl[j] = *(const bf16x8*)(wt_lo + woff);
                }
#pragma unroll
                for (int i = 0; i < 4; ++i)
#pragma unroll
                    for (int j = 0; j < 4; ++j) {
                        acc[i][j] = __builtin_amdgcn_mfma_f32_16x16x32_bf16(ah[i], bh[j], acc[i][j], 0, 0, 0);
                        acc[i][j] = __builtin_amdgcn_mfma_f32_16x16x32_bf16(ah[i], bl[j], acc[i][j], 0, 0, 0);
                        acc[i][j] = __builtin_amdgcn_mfma_f32_16x16x32_bf16(al[i], bh[j], acc[i][j], 0, 0, 0);
                    }
            }
        }
    }

    __syncthreads();

    short* ob = smem + w * 4096;
#pragma unroll
    for (int pass = 0; pass < 2; ++pass) {
#pragma unroll
        for (int j = 0; j < 4; ++j) {
            float bv = bias[co0 + cOff + j * 16 + m];
#pragma unroll
            for (int i = 0; i < 4; ++i)
#pragma unroll
                for (int r = 0; r < 4; ++r) {
                    float val = acc[i][j][r] + bv;
                    if (do_lrelu) val = lrelu_f(val);
                    short hi = f2bf(val);
                    short v = pass ? f2bf(val - bf2f((unsigned short)hi)) : hi;
                    ob[(i * 16 + q * 4 + r) * 64 + j * 16 + m] = v;
                }
        }
        short* outp = pass ? out_lo : out_hi;
#pragma unroll
        for (int itr = 0; itr < 8; ++itr) {
            int row = itr * 8 + (lane >> 3);
            int ch  = lane & 7;
            short8 v = *(const short8*)(ob + row * 64 + ch * 8);
            size_t goff = ((size_t)(b * S_LEN + s0 + sOff + row)) * Cout
                          + co0 + cOff + ch * 8;
            *(short8*)(outp + goff) = v;
        }
    }
}

// ---------------------------------------------------------------------------
// VQ argmin via split-bf16 MFMA + FUSED gather/zq/vq-sum epilogue.
// R5's exact proven kernel (de-fused from the conv after R8/R9/R11 all
// showed the conv+VQ fusion spills under any launch-bounds setting).
// Dead idx_out int write dropped (idx_f is the graded output).
// ---------------------------------------------------------------------------
__global__ __launch_bounds__(256) void vq_mfma_kernel(
        const short* __restrict__ z_hi, const short* __restrict__ z_lo,
        const short* __restrict__ cb_hi, const short* __restrict__ cb_lo,
        const float* __restrict__ cnorm, const float* __restrict__ cb,
        float* __restrict__ idx_f_out, short* __restrict__ zq,
        float* __restrict__ acc_vq) {
    __shared__ short smem[2 * 64 * 136];
    __shared__ float redv[64][4];
    __shared__ int   redi[64][4];
    __shared__ int   idxs[64];
    __shared__ float wsum2[4];
    short* Zh = smem;
    short* Zl = smem + 64 * 136;

    const int tid = threadIdx.x;
    const int lane = tid & 63;
    const int w = tid >> 6;
    const int m = lane & 15;
    const int q = lane >> 4;
    const int n0 = blockIdx.x * 64;

    for (int c = tid; c < 2048; c += 256) {
        int buf = c >> 10;
        int rem = c & 1023;
        int r = rem >> 4, part = rem & 15;
        size_t goff = (size_t)(n0 + r) * DCH + part * 8;
        float4 v = buf ? *(const float4*)(z_lo + goff) : *(const float4*)(z_hi + goff);
        *(float4*)((buf ? Zl : Zh) + r * 136 + part * 8) = v;
    }
    __syncthreads();

    float best[4][4];
    int besti[4][4];
#pragma unroll
    for (int i = 0; i < 4; ++i)
#pragma unroll
        for (int r = 0; r < 4; ++r) { best[i][r] = FLT_MAX; besti[i][r] = 0; }

    for (int k0 = 0; k0 < KCODES; k0 += 256) {
        f32x4 acc[4][4];
        f32x4 zero4 = {0.f, 0.f, 0.f, 0.f};
#pragma unroll
        for (int i = 0; i < 4; ++i)
#pragma unroll
            for (int j = 0; j < 4; ++j) acc[i][j] = zero4;

#pragma unroll
        for (int d0 = 0; d0 < DCH; d0 += 32) {
            bf16x8 ah[4], al[4], bh[4], bl[4];
#pragma unroll
            for (int i = 0; i < 4; ++i) {
                int row = i * 16 + m;
                ah[i] = *(const bf16x8*)(Zh + row * 136 + d0 + q * 8);
                al[i] = *(const bf16x8*)(Zl + row * 136 + d0 + q * 8);
            }
#pragma unroll
            for (int j = 0; j < 4; ++j) {
                size_t coff = (size_t)(k0 + w * 64 + j * 16 + m) * DCH + d0 + q * 8;
                bh[j] = *(const bf16x8*)(cb_hi + coff);
                bl[j] = *(const bf16x8*)(cb_lo + coff);
            }
#pragma unroll
            for (int i = 0; i < 4; ++i)
#pragma unroll
                for (int j = 0; j < 4; ++j) {
                    acc[i][j] = __builtin_amdgcn_mfma_f32_16x16x32_bf16(ah[i], bh[j], acc[i][j], 0, 0, 0);
                    acc[i][j] = __builtin_amdgcn_mfma_f32_16x16x32_bf16(ah[i], bl[j], acc[i][j], 0, 0, 0);
                    acc[i][j] = __builtin_amdgcn_mfma_f32_16x16x32_bf16(al[i], bh[j], acc[i][j], 0, 0, 0);
                }
        }
#pragma unroll
        for (int j = 0; j < 4; ++j) {
            int k = k0 + w * 64 + j * 16 + m;
            float cn = cnorm[k];
#pragma unroll
            for (int i = 0; i < 4; ++i)
#pragma unroll
                for (int r = 0; r < 4; ++r) {
                    float dv = cn - 2.f * acc[i][j][r];
                    if (dv < best[i][r]) { best[i][r] = dv; besti[i][r] = k; }
                }
        }
    }

#pragma unroll
    for (int mask = 1; mask < 16; mask <<= 1) {
#pragma unroll
        for (int i = 0; i < 4; ++i)
#pragma unroll
            for (int r = 0; r < 4; ++r) {
                float ov = __shfl_xor(best[i][r], mask);
                int oi = __shfl_xor(besti[i][r], mask);
                if (ov < best[i][r] || (ov == best[i][r] && oi < besti[i][r])) {
                    best[i][r] = ov; besti[i][r] = oi;
                }
            }
    }
    if (m == 0) {
#pragma unroll
        for (int i = 0; i < 4; ++i)
#pragma unroll
            for (int r = 0; r < 4; ++r) {
                int srow = i * 16 + q * 4 + r;
                redv[srow][w] = best[i][r];
                redi[srow][w] = besti[i][r];
            }
    }
    __syncthreads();
    if (tid < 64) {
        float bv = redv[tid][0];
        int bi = redi[tid][0];
#pragma unroll
        for (int w2 = 1; w2 < 4; ++w2) {
            float v = redv[tid][w2];
            int ii = redi[tid][w2];
            if (v < bv || (v == bv && ii < bi)) { bv = v; bi = ii; }
        }
        idx_f_out[n0 + tid] = (float)bi;
        idxs[tid] = bi;
    }
    __syncthreads();

    // Fused gather + vq-sum epilogue: 4 threads per row, 32 d each.
    // Zh/Zl still hold this block's z tile (untouched since staging).
    {
        int r = tid >> 2;
        int dpart = tid & 3;
        int k = idxs[r];
        const float* src = cb + (size_t)k * DCH + dpart * 32;
        const short* zh = Zh + r * 136 + dpart * 32;
        const short* zl = Zl + r * 136 + dpart * 32;
        size_t zoff = (size_t)(n0 + r) * DCH + dpart * 32;
        float sum = 0.f;
#pragma unroll
        for (int h = 0; h < 4; ++h) {
            float4 f0 = *(const float4*)(src + h * 8);
            float4 f1 = *(const float4*)(src + h * 8 + 4);
            bf16x8 vh = *(const bf16x8*)(zh + h * 8);
            bf16x8 vl = *(const bf16x8*)(zl + h * 8);
            float qv[8] = {f0.x, f0.y, f0.z, f0.w, f1.x, f1.y, f1.z, f1.w};
            short8 o;
#pragma unroll
            for (int e = 0; e < 8; ++e) {
                o[e] = f2bf(qv[e]);
                float zv = bf2f((unsigned short)vh[e]) + bf2f((unsigned short)vl[e]);
                float df = zv - qv[e];
                sum += df * df;
            }
            *(short8*)(zq + zoff + h * 8) = o;
        }
        for (int off = 32; off > 0; off >>= 1) sum += __shfl_down(sum, off);
        if (lane == 0) wsum2[w] = sum;
    }
    __syncthreads();
    if (tid == 0) atomicAdd(acc_vq, wsum2[0] + wsum2[1] + wsum2[2] + wsum2[3]);
}

// ---------------------------------------------------------------------------
// Decoder bf16 MFMA conv (channels-last) -- R5 original (492us-best run).
// ---------------------------------------------------------------------------
__global__ __launch_bounds__(256) void conv_mfma_cl(
        const short* __restrict__ in, short* __restrict__ out,
        const short* __restrict__ wt, const float* __restrict__ bias,
        int Cin) {
    __shared__ short smem[24672];
    short* Xs = smem;
    short* Ws = smem + 130 * 48;

    const int tid = threadIdx.x;
    const int lane = tid & 63;
    const int w = tid >> 6;
    const int m = lane & 15;
    const int q = lane >> 4;
    const int sOff = (w & 1) * 64;
    const int cOff = (w >> 1) * 64;
    const int b = blockIdx.z;
    const int s0 = blockIdx.x * 128;
    const int co0 = blockIdx.y * 128;

    f32x4 acc[4][4];
    f32x4 zero4 = {0.f, 0.f, 0.f, 0.f};
#pragma unroll
    for (int i = 0; i < 4; ++i)
#pragma unroll
        for (int j = 0; j < 4; ++j) acc[i][j] = zero4;

    const short* inb = in + (size_t)b * S_LEN * Cin;

    for (int ci0 = 0; ci0 < Cin; ci0 += 32) {
        __syncthreads();
        for (int c = tid; c < 520; c += 256) {
            int r = c >> 2, part = c & 3;
            int s = s0 - 1 + r;
            float4 v = make_float4(0.f, 0.f, 0.f, 0.f);
            if (s >= 0 && s < S_LEN)
                v = *(const float4*)(inb + (size_t)s * Cin + ci0 + part * 8);
            *(float4*)(Xs + r * 48 + part * 8) = v;
        }
        for (int c = tid; c < 1536; c += 256) {
            int t = c >> 9;
            int rem = c & 511;
            int cr = rem >> 2, part = rem & 3;
            float4 v = *(const float4*)(wt + ((size_t)(t * 256 + co0 + cr)) * Cin + ci0 + part * 8);
            *(float4*)(Ws + (t * 128 + cr) * 48 + part * 8) = v;
        }
        __syncthreads();

#pragma unroll
        for (int t = 0; t < 3; ++t) {
            bf16x8 a[4], bb[4];
#pragma unroll
            for (int i = 0; i < 4; ++i)
                a[i] = *(const bf16x8*)(Xs + (sOff + i * 16 + m + t) * 48 + q * 8);
#pragma unroll
            for (int j = 0; j < 4; ++j)
                bb[j] = *(const bf16x8*)(Ws + (t * 128 + cOff + j * 16 + m) * 48 + q * 8);
#pragma unroll
            for (int i = 0; i < 4; ++i)
#pragma unroll
                for (int j = 0; j < 4; ++j)
                    acc[i][j] = __builtin_amdgcn_mfma_f32_16x16x32_bf16(
                        a[i], bb[j], acc[i][j], 0, 0, 0);
        }
    }

    __syncthreads();

    short* ob = smem + w * (64 * 80);
#pragma unroll
    for (int j = 0; j < 4; ++j) {
        float bv = bias[co0 + cOff + j * 16 + m];
#pragma unroll
        for (int i = 0; i < 4; ++i) {
#pragma unroll
            for (int r = 0; r < 4; ++r) {
                float val = acc[i][j][r] + bv;
                val = lrelu_f(val);
                ob[(i * 16 + q * 4 + r) * 80 + j * 16 + m] = f2bf(val);
            }
        }
    }
    const int rsel = lane >> 3;
    const int off8 = (lane & 7) * 8;
#pragma unroll
    for (int pass = 0; pass < 8; ++pass) {
        int rr = pass * 8 + rsel;
        short8 v = *(const short8*)(ob + rr * 80 + off8);
        *(short8*)(out + ((size_t)(b * S_LEN + s0 + sOff + rr)) * 256 + co0 + cOff + off8) = v;
    }
}

// ---------------------------------------------------------------------------
// Decoder conv3, LDS-tiled: h[B][S][256] bf16 -> xr[B][S] fp32, + recon sum.
// ---------------------------------------------------------------------------
__global__ __launch_bounds__(256) void dec_conv3_tiled_kernel(
        const short* __restrict__ h, const float* __restrict__ w3t,
        const float* __restrict__ b3, const float* __restrict__ x,
        float* __restrict__ xr, float* __restrict__ acc_recon) {
    __shared__ short Zs[66 * 264];     // 34,848 B
    __shared__ float ws[3 * 256];
    __shared__ float wsum[4];
    int tid = threadIdx.x;
    int b = blockIdx.y;
    int s0 = blockIdx.x * 64;
    const short* hb = h + (size_t)b * S_LEN * HCH;
    for (int i = tid; i < 768; i += 256) ws[i] = w3t[i];
    for (int c = tid; c < 2112; c += 256) {
        int r = c >> 5, part = c & 31;
        int g = s0 - 1 + r;
        short8 v = {0, 0, 0, 0, 0, 0, 0, 0};
        if (g >= 0 && g < S_LEN)
            v = *(const short8*)(hb + (size_t)g * HCH + part * 8);
        *(short8*)(Zs + r * 264 + part * 8) = v;
    }
    __syncthreads();

    int quarter = tid & 3;
    int sl = tid >> 2;   // 0..63
    float a0 = 0.f, a1 = 0.f, a2 = 0.f, a3 = 0.f;
#pragma unroll
    for (int t = 0; t < 3; ++t) {
        const short* zrow = Zs + (sl + t) * 264 + quarter * 64;
        const float* wrow = ws + t * 256 + quarter * 64;
#pragma unroll
        for (int c = 0; c < 8; ++c) {
            bf16x8 v = *(const bf16x8*)(zrow + c * 8);
            float4 w0 = *(const float4*)(wrow + c * 8);
            float4 w1 = *(const float4*)(wrow + c * 8 + 4);
            a0 = fmaf(w0.x, bf2f((unsigned short)v[0]), a0);
            a1 = fmaf(w0.y, bf2f((unsigned short)v[1]), a1);
            a2 = fmaf(w0.z, bf2f((unsigned short)v[2]), a2);
            a3 = fmaf(w0.w, bf2f((unsigned short)v[3]), a3);
            a0 = fmaf(w1.x, bf2f((unsigned short)v[4]), a0);
            a1 = fmaf(w1.y, bf2f((unsigned short)v[5]), a1);
            a2 = fmaf(w1.z, bf2f((unsigned short)v[6]), a2);
            a3 = fmaf(w1.w, bf2f((unsigned short)v[7]), a3);
        }
    }
    float acc = (a0 + a1) + (a2 + a3);
    acc += __shfl_xor(acc, 1);
    acc += __shfl_xor(acc, 2);
    float df2 = 0.f;
    if (quarter == 0) {
        int s = s0 + sl;
        float tot = acc + b3[0];
        xr[b * S_LEN + s] = tot;
        float df = x[b * S_LEN + s] - tot;
        df2 = df * df;
    }
    for (int off = 32; off > 0; off >>= 1) df2 += __shfl_down(df2, off);
    int lane = tid & 63, wv = tid >> 6;
    if (lane == 0) wsum[wv] = df2;
    __syncthreads();
    if (tid == 0) atomicAdd(acc_recon, wsum[0] + wsum[1] + wsum[2] + wsum[3]);
}

// ---------------------------------------------------------------------------
__global__ void finalize_kernel(const float* __restrict__ accs, float* __restrict__ out) {
    if (threadIdx.x == 0) {
        float vqm = accs[0] / ((float)BATCH * S_LEN * DCH);
        float rm  = accs[1] / ((float)BATCH * S_LEN);
        float vq_loss = vqm * 0.05f;
        float commit  = vqm * 0.15f;
        float recon   = rm * 1.0f;
        out[0] = recon + vq_loss + commit;
        out[1] = recon;
        out[2] = vq_loss;
        out[3] = commit;
    }
}

// ---------------------------------------------------------------------------
extern "C" void kernel_launch(void* const* d_in, const int* in_sizes, int n_in,
                              void* d_out, int out_size, void* d_ws, size_t ws_size,
                              hipStream_t stream) {
    const float* x    = (const float*)d_in[0];
    const float* cb   = (const float*)d_in[1];
    const float* ew1  = (const float*)d_in[2];
    const float* eb1  = (const float*)d_in[3];
    const float* ew2  = (const float*)d_in[4];
    const float* eb2  = (const float*)d_in[5];
    const float* ew3  = (const float*)d_in[6];
    const float* eb3  = (const float*)d_in[7];
    const float* dw1  = (const float*)d_in[8];
    const float* db1  = (const float*)d_in[9];
    const float* dw2  = (const float*)d_in[10];
    const float* db2  = (const float*)d_in[11];
    const float* dw3  = (const float*)d_in[12];
    const float* db3  = (const float*)d_in[13];

    float* out = (float*)d_out;
    float* xr    = out;
    float* idx_f = out + BATCH * S_LEN;
    float* loss_out = out + 2 * BATCH * S_LEN;

    const size_t NH = (size_t)BATCH * S_LEN * HCH;   // 16,777,216
    const size_t ND = (size_t)BATCH * S_LEN * DCH;   // 8,388,608

    short* sp = (short*)d_ws;
    // arena A [0, 2*NH): h1 hi/lo -> z hi/lo (h1 dead after conv2) -> h1d
    short* h1_hi = sp;
    short* h1_lo = sp + NH;
    short* z_hi  = sp;            // overlays h1
    short* z_lo  = sp + ND;
    short* h1d_bf = sp;           // overlays z (dead after vq)
    // arena B [2*NH, 4*NH): h2 hi/lo -> zq + h2d
    short* h2_hi = sp + 2 * NH;
    short* h2_lo = sp + 3 * NH;
    short* zq_bf = sp + 2 * NH;   // overlays h2_hi (dead after conv3-enc)
    short* h2d_bf = sp + 3 * NH;  // overlays h2_lo
    // small buffers
    short* sm = sp + 4 * NH;
    short* cb_hi = sm; sm += KCODES * DCH;
    short* cb_lo = sm; sm += KCODES * DCH;
    short* w2_hi = sm; sm += 3 * HCH * HCH;
    short* w2_lo = sm; sm += 3 * HCH * HCH;
    short* w3_hi = sm; sm += 3 * DCH * HCH;
    short* w3_lo = sm; sm += 3 * DCH * HCH;
    short* wbf_d1 = sm; sm += 3 * 256 * DCH;
    short* wbf_d2 = sm; sm += 3 * 256 * HCH;
    float* cnorm = (float*)sm;
    float* w3t = cnorm + KCODES;
    float* accs = w3t + 768;

    hipMemsetAsync(accs, 0, 2 * sizeof(float), stream);

    // single fused prep launch (proven R8/R11)
    prep_all_kernel<<<dim3(768, 6), 256, 0, stream>>>(
        cb, cb_hi, cb_lo, cnorm, ew2, w2_hi, w2_lo, ew3, w3_hi, w3_lo,
        dw1, wbf_d1, dw2, wbf_d2, dw3, w3t);

    // encoder (split-bf16 MFMA, v6)
    enc_conv1_cl_kernel<<<dim3(S_LEN / 32, BATCH), 256, 0, stream>>>(x, h1_hi, h1_lo, ew1, eb1);
    conv_mfma_split<<<dim3(S_LEN / 128, HCH / 128, BATCH), 256, 0, stream>>>(
        h1_hi, h1_lo, h2_hi, h2_lo, w2_hi, w2_lo, eb2, HCH, HCH, 1);
    conv_mfma_split<<<dim3(S_LEN / 128, DCH / 128, BATCH), 256, 0, stream>>>(
        h2_hi, h2_lo, z_hi, z_lo, w3_hi, w3_lo, eb3, HCH, DCH, 0);

    // VQ (argmin + fused gather/zq/vq-sum) -- R5 proven
    vq_mfma_kernel<<<(BATCH * S_LEN) / 64, 256, 0, stream>>>(
        z_hi, z_lo, cb_hi, cb_lo, cnorm, cb, idx_f, zq_bf, accs);

    // decoder (R5-original cl kernels)
    conv_mfma_cl<<<dim3(S_LEN / 128, 2, BATCH), 256, 0, stream>>>(
        zq_bf, h1d_bf, wbf_d1, db1, DCH);
    conv_mfma_cl<<<dim3(S_LEN / 128, 2, BATCH), 256, 0, stream>>>(
        h1d_bf, h2d_bf, wbf_d2, db2, HCH);
    dec_conv3_tiled_kernel<<<dim3(S_LEN / 64, BATCH), 256, 0, stream>>>(
        h2d_bf, w3t, db3, x, xr, accs + 1);

    finalize_kernel<<<1, 64, 0, stream>>>(accs, loss_out);
}